// Round 2
// baseline (413.189 us; speedup 1.0000x reference)
//
#include <hip/hip_runtime.h>

#define Bb 4
#define Ll 2048
#define Dd 1024
#define Mm (Bb*Ll)          // 8192 rows
#define NCH 64              // scan chunks
#define CLEN (Ll/NCH)       // 32 steps per chunk

typedef __attribute__((ext_vector_type(4))) float f32x4;
typedef __attribute__((ext_vector_type(8))) short s16x8;
typedef __attribute__((ext_vector_type(4))) short s16x4;

__device__ __forceinline__ float sigm(float v){ return 1.0f/(1.0f+__expf(-v)); }

__device__ __forceinline__ short bf16rne(float f){
  unsigned u = __builtin_bit_cast(unsigned, f);
  u += 0x7fffu + ((u>>16)&1u);
  return (short)(u>>16);
}

__device__ __forceinline__ void gl_lds16(const void* g, void* l){
  __builtin_amdgcn_global_load_lds((__attribute__((address_space(1))) void*)g,
                                   (__attribute__((address_space(3))) void*)l, 16, 0, 0);
}

// C[m,n] = sum_k A[m,k] * W[n,k]   (both K-contiguous, "B^T" GEMM)
// EPI: 0=lambda  1=beta(phi)  2=alpha(sigmoid)  3=rho-blend->bf16  4=residual out
template<int EPI>
__launch_bounds__(256)
__global__ void gemm_bt(const short* __restrict__ A0, const short* __restrict__ A1,
                        const short* __restrict__ A2, const short* __restrict__ W,
                        int K,
                        const float* __restrict__ v0, const float* __restrict__ p0,
                        const float* __restrict__ p1,
                        float* __restrict__ of, short* __restrict__ oh)
{
  __shared__ short As[128*32];
  __shared__ short Bs[128*32];
  const int tid  = threadIdx.x;
  const int lane = tid & 63;
  const int wid  = tid >> 6;
  const int wm = wid >> 1, wn = wid & 1;
  const long bm0 = (long)blockIdx.x * 128;
  const long bn0 = (long)blockIdx.y * 128;

  f32x4 acc[4][4] = {};

  const int r0 = tid >> 2;           // staging row, chunk it=0
  const int r1 = (256 + tid) >> 2;   // chunk it=1
  const int sg = (tid & 3) * 8;      // k-segment (8 bf16 = 16B)

  for (int k0 = 0; k0 < K; k0 += 32) {
    const short* Asrc = A0; long acol = k0;
    if (EPI == 3) {
      const int blk = k0 >> 10;
      Asrc = (blk == 0) ? A0 : ((blk == 1) ? A1 : A2);
      acol = k0 & 1023;
    }
    gl_lds16(Asrc + (bm0 + r0)*1024 + acol + sg, As + tid*8);
    gl_lds16(Asrc + (bm0 + r1)*1024 + acol + sg, As + (256 + tid)*8);
    gl_lds16(W + (bn0 + r0)*(long)K + k0 + sg, Bs + tid*8);
    gl_lds16(W + (bn0 + r1)*(long)K + k0 + sg, Bs + (256 + tid)*8);
    __syncthreads();   // drains vmcnt(0) -> LDS tiles ready

    s16x8 af[4], bf[4];
    #pragma unroll
    for (int mi = 0; mi < 4; ++mi)
      af[mi] = *(const s16x8*)&As[(wm*64 + mi*16 + (lane & 15))*32 + (lane >> 4)*8];
    #pragma unroll
    for (int ni = 0; ni < 4; ++ni)
      bf[ni] = *(const s16x8*)&Bs[(wn*64 + ni*16 + (lane & 15))*32 + (lane >> 4)*8];

    #pragma unroll
    for (int mi = 0; mi < 4; ++mi)
      #pragma unroll
      for (int ni = 0; ni < 4; ++ni)
        asm("v_mfma_f32_16x16x32_bf16 %0, %1, %2, %0"
            : "+v"(acc[mi][ni]) : "v"(af[mi]), "v"(bf[ni]));
    __syncthreads();   // protect LDS before next staging
  }

  const float rs = (EPI == 4) ? p1[0] : 0.0f;
  const int ecol0 = (int)bn0 + wn*64 + (lane & 15);
  const int erow0 = (int)bm0 + wm*64 + ((lane >> 4) << 2);

  #pragma unroll
  for (int mi = 0; mi < 4; ++mi) {
    #pragma unroll
    for (int ni = 0; ni < 4; ++ni) {
      // MFMA->VALU read hazard fence (inline-asm MFMA: compiler can't insert nops)
      asm volatile("s_nop 7\n\ts_nop 7\n\ts_nop 7" : "+v"(acc[mi][ni]));
      const f32x4 v = acc[mi][ni];
      const int gn = ecol0 + ni*16;
      #pragma unroll
      for (int j = 0; j < 4; ++j) {
        const long gm  = erow0 + mi*16 + j;
        const long idx = gm*1024 + gn;
        const float val = v[j];
        if (EPI == 0) {
          float z = val + v0[gn];
          z = fminf(fmaxf(z, -4.0f), 4.0f);
          float l = __expf(-__expf(z));
          of[idx] = fminf(fmaxf(l, 0.001f), 0.999f);
        } else if (EPI == 1) {
          of[idx] = val*sigm(val) + 0.1f*__sinf(val);
        } else if (EPI == 2) {
          of[idx] = sigm(val + v0[gn]);
        } else if (EPI == 3) {
          const float r = sigm(val + v0[gn]);
          const float h = r*p0[idx] + (1.0f - r)*p1[idx];
          oh[idx] = bf16rne(h);
        } else {
          of[idx] = p0[idx] + rs*val;
        }
      }
    }
  }
}

// ---------- chunked linear-recurrence scan: h_t = l_t*h_{t-1} + b_t ----------

__global__ void f_chunk1(const float* __restrict__ lm, const float* __restrict__ bgp,
                         const float* __restrict__ fprev,
                         float* __restrict__ cP, float* __restrict__ cB)
{
  const int d = blockIdx.x*256 + threadIdx.x;
  const int c = blockIdx.y, b = blockIdx.z;
  float P = 1.0f, Bv = 0.0f;
  size_t base = ((size_t)b*Ll + (size_t)c*CLEN)*Dd + d;
  const float fp = (c == 0) ? fprev[b*Dd + d] : 0.0f;
  for (int t = 0; t < CLEN; ++t) {
    const float l = lm[base];
    float bb = bgp[base];
    if (c == 0 && t == 0) bb += l*fp;   // inject f_prev into step 0
    P *= l;
    Bv = l*Bv + bb;
    base += Dd;
  }
  const size_t ci = ((size_t)b*NCH + c)*Dd + d;
  cP[ci] = P; cB[ci] = Bv;
}

__global__ void scan_carry(const float* __restrict__ cP, const float* __restrict__ cB,
                           const float* __restrict__ init,
                           float* __restrict__ H0, float* __restrict__ last_out)
{
  const int d = blockIdx.x*256 + threadIdx.x;
  const int b = blockIdx.y;
  float h = init ? init[b*Dd + d] : 0.0f;
  for (int c = 0; c < NCH; ++c) {
    const size_t ci = ((size_t)b*NCH + c)*Dd + d;
    H0[ci] = h;
    h = cP[ci]*h + cB[ci];
  }
  last_out[b*Dd + d] = h;   // state at t = L-1
}

__global__ void f_chunk3(const float* __restrict__ lm, const float* __restrict__ bgp,
                         const float* __restrict__ fprev, const float* __restrict__ H0,
                         float* __restrict__ fo, short* __restrict__ fob)
{
  const int d = blockIdx.x*256 + threadIdx.x;
  const int c = blockIdx.y, b = blockIdx.z;
  float h = H0[((size_t)b*NCH + c)*Dd + d];
  size_t base = ((size_t)b*Ll + (size_t)c*CLEN)*Dd + d;
  const float fp = (c == 0) ? fprev[b*Dd + d] : 0.0f;
  for (int t = 0; t < CLEN; ++t) {
    const float l = lm[base];
    float bb = bgp[base];
    if (c == 0 && t == 0) bb += l*fp;
    h = l*h + bb;
    fo[base] = h;
    fob[base] = bf16rne(h);
    base += Dd;
  }
}

__global__ void s_chunk1(const float* __restrict__ alp, const float* __restrict__ fst,
                         float* __restrict__ cP, float* __restrict__ cB)
{
  const int d = blockIdx.x*256 + threadIdx.x;
  const int c = blockIdx.y, b = blockIdx.z;
  float P = 1.0f, Bv = 0.0f;
  size_t base = ((size_t)b*Ll + (size_t)c*CLEN)*Dd + d;
  for (int t = 0; t < CLEN; ++t) {
    const float a = alp[base];
    const float l = 1.0f - a;
    P *= l;
    Bv = l*Bv + a*fst[base];
    base += Dd;
  }
  const size_t ci = ((size_t)b*NCH + c)*Dd + d;
  cP[ci] = P; cB[ci] = Bv;
}

__global__ void s_chunk3(const float* __restrict__ alp, const float* __restrict__ fst,
                         const float* __restrict__ H0,
                         float* __restrict__ so, short* __restrict__ sob)
{
  const int d = blockIdx.x*256 + threadIdx.x;
  const int c = blockIdx.y, b = blockIdx.z;
  float h = H0[((size_t)b*NCH + c)*Dd + d];
  size_t base = ((size_t)b*Ll + (size_t)c*CLEN)*Dd + d;
  for (int t = 0; t < CLEN; ++t) {
    const float a = alp[base];
    h = h + a*(fst[base] - h);
    so[base] = h;
    sob[base] = bf16rne(h);
    base += Dd;
  }
}

__global__ void cvt_bf16(const float* __restrict__ src, short* __restrict__ dst, int n4)
{
  int i = blockIdx.x*256 + threadIdx.x;
  const int stride = gridDim.x*256;
  for (; i < n4; i += stride) {
    const f32x4 v = ((const f32x4*)src)[i];
    s16x4 o;
    o[0] = bf16rne(v[0]); o[1] = bf16rne(v[1]);
    o[2] = bf16rne(v[2]); o[3] = bf16rne(v[3]);
    ((s16x4*)dst)[i] = o;
  }
}

extern "C" void kernel_launch(void* const* d_in, const int* in_sizes, int n_in,
                              void* d_out, int out_size, void* d_ws, size_t ws_size,
                              hipStream_t stream)
{
  (void)in_sizes; (void)n_in; (void)out_size; (void)ws_size;
  const float* x   = (const float*)d_in[0];
  const float* fpv = (const float*)d_in[1];
  const float* spv = (const float*)d_in[2];
  const float* wl  = (const float*)d_in[3];
  const float* Pw  = (const float*)d_in[4];
  const float* Wbw = (const float*)d_in[5];
  const float* Waw = (const float*)d_in[6];
  const float* ab  = (const float*)d_in[7];
  const float* Wr  = (const float*)d_in[8];
  const float* rb  = (const float*)d_in[9];
  const float* Wo  = (const float*)d_in[10];
  const float* rs  = (const float*)d_in[11];

  float* out    = (float*)d_out;
  float* f_last = out + (size_t)Mm*Dd;
  float* s_last = f_last + (size_t)Bb*Dd;

  char* w = (char*)d_ws;
  auto alloc = [&](size_t bytes){ char* p = w; w += (bytes + 255) & ~(size_t)255; return p; };
  short* xb   = (short*)alloc((size_t)Mm*Dd*2);
  short* pb   = (short*)alloc((size_t)Dd*Dd*2);
  short* wbb  = (short*)alloc((size_t)Dd*Dd*2);
  short* wab  = (short*)alloc((size_t)Dd*Dd*2);
  short* wrb  = (short*)alloc((size_t)Dd*3*Dd*2);
  short* opb  = (short*)alloc((size_t)Dd*Dd*2);
  float* lam  = (float*)alloc((size_t)Mm*Dd*4);
  float* bg   = (float*)alloc((size_t)Mm*Dd*4);
  float* al   = (float*)alloc((size_t)Mm*Dd*4);
  float* f32f = (float*)alloc((size_t)Mm*Dd*4);
  float* s32  = (float*)alloc((size_t)Mm*Dd*4);
  short* fb   = (short*)alloc((size_t)Mm*Dd*2);
  short* sb   = (short*)alloc((size_t)Mm*Dd*2);
  float* cP   = (float*)alloc((size_t)Bb*NCH*Dd*4);
  float* cB   = (float*)alloc((size_t)Bb*NCH*Dd*4);
  float* H0   = (float*)alloc((size_t)Bb*NCH*Dd*4);
  short* hm   = (short*)lam;   // alias: lam dead before rho-GEMM writes h_mid

  auto cvt = [&](const float* s_, short* d_, size_t n){
    int n4 = (int)(n/4);
    int grid = (n4 + 255)/256; if (grid > 2048) grid = 2048;
    cvt_bf16<<<dim3(grid), dim3(256), 0, stream>>>(s_, d_, n4);
  };
  cvt(x,   xb,  (size_t)Mm*Dd);
  cvt(Pw,  pb,  (size_t)Dd*Dd);
  cvt(Wbw, wbb, (size_t)Dd*Dd);
  cvt(Waw, wab, (size_t)Dd*Dd);
  cvt(Wr,  wrb, (size_t)Dd*3*Dd);
  cvt(Wo,  opb, (size_t)Dd*Dd);

  const dim3 gg(Mm/128, Dd/128);
  gemm_bt<0><<<gg, dim3(256), 0, stream>>>(xb, nullptr, nullptr, pb,  Dd,   wl, nullptr, nullptr, lam, nullptr);
  gemm_bt<1><<<gg, dim3(256), 0, stream>>>(xb, nullptr, nullptr, wbb, Dd,   nullptr, nullptr, nullptr, bg, nullptr);
  gemm_bt<2><<<gg, dim3(256), 0, stream>>>(xb, nullptr, nullptr, wab, Dd,   ab, nullptr, nullptr, al, nullptr);

  const dim3 gs(Dd/256, NCH, Bb);
  const dim3 gc(Dd/256, Bb);
  f_chunk1<<<gs, dim3(256), 0, stream>>>(lam, bg, fpv, cP, cB);
  scan_carry<<<gc, dim3(256), 0, stream>>>(cP, cB, (const float*)nullptr, H0, f_last);
  f_chunk3<<<gs, dim3(256), 0, stream>>>(lam, bg, fpv, H0, f32f, fb);

  s_chunk1<<<gs, dim3(256), 0, stream>>>(al, f32f, cP, cB);
  scan_carry<<<gc, dim3(256), 0, stream>>>(cP, cB, spv, H0, s_last);
  s_chunk3<<<gs, dim3(256), 0, stream>>>(al, f32f, H0, s32, sb);

  gemm_bt<3><<<gg, dim3(256), 0, stream>>>(fb, sb, xb, wrb, 3*Dd, rb, f32f, s32, nullptr, hm);
  gemm_bt<4><<<gg, dim3(256), 0, stream>>>(hm, nullptr, nullptr, opb, Dd, nullptr, x, rs, out, nullptr);
}

// Round 3
// 389.860 us; speedup vs baseline: 1.0598x; 1.0598x over previous
//
#include <hip/hip_runtime.h>

#define Bb 4
#define Ll 2048
#define Dd 1024
#define Mm (Bb*Ll)          // 8192 rows
#define NCH 64              // scan chunks
#define CLEN (Ll/NCH)       // 32 steps per chunk

typedef __attribute__((ext_vector_type(4))) float f32x4;
typedef __attribute__((ext_vector_type(8))) short s16x8;
typedef __attribute__((ext_vector_type(4))) short s16x4;

__device__ __forceinline__ float sigm(float v){ return 1.0f/(1.0f+__expf(-v)); }

__device__ __forceinline__ short bf16rne(float f){
  unsigned u = __builtin_bit_cast(unsigned, f);
  u += 0x7fffu + ((u>>16)&1u);
  return (short)(u>>16);
}
__device__ __forceinline__ float bf2f(short s){
  unsigned u = ((unsigned)(unsigned short)s) << 16;
  return __builtin_bit_cast(float, u);
}

__device__ __forceinline__ void gl_lds16(const void* g, void* l){
  __builtin_amdgcn_global_load_lds((__attribute__((address_space(1))) void*)g,
                                   (__attribute__((address_space(3))) void*)l, 16, 0, 0);
}

// C[m,n] = sum_k A[m,k] * W[n,k]  (K-contiguous both sides), 2-phase LDS double-buffer.
// EPI: 5=fused phase-1 (lambda|phi|sigmoid by column segment)
//      3=rho-blend->bf16   4=residual out
template<int EPI>
__launch_bounds__(256)
__global__ void gemm_bt(const short* __restrict__ A0, const short* __restrict__ A1,
                        const short* __restrict__ A2, const short* __restrict__ W,
                        int K,
                        const float* __restrict__ b0, const float* __restrict__ b1,
                        const float* __restrict__ xres, const float* __restrict__ rsp,
                        const short* __restrict__ fB, const short* __restrict__ sB,
                        float* __restrict__ oF, short* __restrict__ oB0,
                        short* __restrict__ oB1)
{
  __shared__ short As[2][128*32];
  __shared__ short Bs[2][128*32];
  const int tid  = threadIdx.x;
  const int lane = tid & 63;
  const int wid  = tid >> 6;
  const int wm = wid >> 1, wn = wid & 1;
  const long bn0 = (long)blockIdx.x * 128;   // x = column blocks (A-panel reuse in dispatch order)
  const long bm0 = (long)blockIdx.y * 128;

  f32x4 acc[4][4] = {};

  const int r0 = tid >> 2;           // staging row, chunk 0
  const int r1 = (256 + tid) >> 2;   // staging row, chunk 1
  const int sg = (tid & 3) * 8;      // k-segment (8 bf16 = 16B)

  auto stage = [&](int buf, int k0){
    const short* Asrc = A0; long acol = k0;
    if (EPI == 3) {
      const int blk = k0 >> 10;
      Asrc = (blk == 0) ? A0 : ((blk == 1) ? A1 : A2);
      acol = k0 & 1023;
    }
    gl_lds16(Asrc + (bm0 + r0)*1024 + acol + sg, &As[buf][(size_t)tid*8]);
    gl_lds16(Asrc + (bm0 + r1)*1024 + acol + sg, &As[buf][(size_t)(256+tid)*8]);
    gl_lds16(W + (bn0 + r0)*(long)K + k0 + sg, &Bs[buf][(size_t)tid*8]);
    gl_lds16(W + (bn0 + r1)*(long)K + k0 + sg, &Bs[buf][(size_t)(256+tid)*8]);
  };

  auto compute = [&](int buf){
    s16x8 af[4], bfr[4];
    #pragma unroll
    for (int mi = 0; mi < 4; ++mi)
      af[mi] = *(const s16x8*)&As[buf][(wm*64 + mi*16 + (lane & 15))*32 + (lane >> 4)*8];
    #pragma unroll
    for (int ni = 0; ni < 4; ++ni)
      bfr[ni] = *(const s16x8*)&Bs[buf][(wn*64 + ni*16 + (lane & 15))*32 + (lane >> 4)*8];
    #pragma unroll
    for (int mi = 0; mi < 4; ++mi)
      #pragma unroll
      for (int ni = 0; ni < 4; ++ni)
        asm("v_mfma_f32_16x16x32_bf16 %0, %1, %2, %0"
            : "+v"(acc[mi][ni]) : "v"(af[mi]), "v"(bfr[ni]));
  };

  // 2-phase pipeline: stage(k+1) issued before compute(k); __syncthreads drains
  // vmcnt(0)+lgkmcnt(0), so next tile is ready and this buffer is safe to reuse.
  stage(0, 0);
  __syncthreads();
  int cur = 0;
  for (int k0 = 32; k0 < K; k0 += 32) {
    stage(cur ^ 1, k0);
    compute(cur);
    __syncthreads();
    cur ^= 1;
  }
  compute(cur);

  const float rs = (EPI == 4) ? rsp[0] : 0.0f;
  const int seg = (EPI == 5) ? (int)(bn0 >> 10) : 0;
  const int ecol0 = (int)bn0 + wn*64 + (lane & 15);
  const int erow0 = (int)bm0 + wm*64 + ((lane >> 4) << 2);

  #pragma unroll
  for (int mi = 0; mi < 4; ++mi) {
    #pragma unroll
    for (int ni = 0; ni < 4; ++ni) {
      // MFMA->VALU read hazard fence (inline-asm MFMA: compiler can't insert nops)
      asm volatile("s_nop 7\n\ts_nop 7\n\ts_nop 7" : "+v"(acc[mi][ni]));
      const f32x4 v = acc[mi][ni];
      const int gn = ecol0 + ni*16;
      const int cn = gn & 1023;
      #pragma unroll
      for (int j = 0; j < 4; ++j) {
        const long gm  = erow0 + mi*16 + j;
        const long idx = gm*1024 + cn;
        const float val = v[j];
        if (EPI == 5) {
          if (seg == 0) {            // lambda (f32: error amplified ~1/(1-lam))
            float z = val + b0[cn];
            z = fminf(fmaxf(z, -4.0f), 4.0f);
            float l = __expf(-__expf(z));
            oF[idx] = fminf(fmaxf(l, 0.001f), 0.999f);
          } else if (seg == 1) {     // B gate: phi = silu + 0.1 sin
            oB0[idx] = bf16rne(val*sigm(val) + 0.1f*__sinf(val));
          } else {                   // alpha
            oB1[idx] = bf16rne(sigm(val + b1[cn]));
          }
        } else if (EPI == 3) {
          const float r = sigm(val + b0[cn]);
          const float f = bf2f(fB[idx]);
          const float s = bf2f(sB[idx]);
          oB0[idx] = bf16rne(r*f + (1.0f - r)*s);
        } else {
          oF[idx] = xres[idx] + rs*val;
        }
      }
    }
  }
}

// ---------- chunked linear-recurrence scans ----------

// f-chunk products: P = prod(lam), B = sum
__global__ void f_chunk1(const float* __restrict__ lm, const short* __restrict__ bgB,
                         const float* __restrict__ fprev,
                         float* __restrict__ cP, float* __restrict__ cB)
{
  const int d = blockIdx.x*256 + threadIdx.x;
  const int c = blockIdx.y, b = blockIdx.z;
  float P = 1.0f, Bv = 0.0f;
  size_t base = ((size_t)b*Ll + (size_t)c*CLEN)*Dd + d;
  const float fp = (c == 0) ? fprev[b*Dd + d] : 0.0f;
  for (int t = 0; t < CLEN; ++t) {
    const float l = lm[base];
    float bb = bf2f(bgB[base]);
    if (c == 0 && t == 0) bb += l*fp;   // inject f_prev into step 0
    P *= l;
    Bv = l*Bv + bb;
    base += Dd;
  }
  const size_t ci = ((size_t)b*NCH + c)*Dd + d;
  cP[ci] = P; cB[ci] = Bv;
}

__global__ void scan_carry(const float* __restrict__ cP, const float* __restrict__ cB,
                           const float* __restrict__ init,
                           float* __restrict__ H0, float* __restrict__ last_out)
{
  const int d = blockIdx.x*256 + threadIdx.x;
  const int b = blockIdx.y;
  float h = init ? init[b*Dd + d] : 0.0f;
  for (int c = 0; c < NCH; ++c) {
    const size_t ci = ((size_t)b*NCH + c)*Dd + d;
    H0[ci] = h;
    h = cP[ci]*h + cB[ci];
  }
  last_out[b*Dd + d] = h;   // state at t = L-1
}

// f replay (writes bf16 f-states) fused with s-chunk product accumulation.
// Uses the bf16-ROUNDED f in the s-accumulation so carry matches s_chunk3 replay.
__global__ void fs_mid(const float* __restrict__ lm, const short* __restrict__ bgB,
                       const float* __restrict__ fprev, const float* __restrict__ H0f,
                       const short* __restrict__ alB,
                       short* __restrict__ fob, float* __restrict__ cPs,
                       float* __restrict__ cBs)
{
  const int d = blockIdx.x*256 + threadIdx.x;
  const int c = blockIdx.y, b = blockIdx.z;
  float h = H0f[((size_t)b*NCH + c)*Dd + d];
  float sP = 1.0f, sBv = 0.0f;
  size_t base = ((size_t)b*Ll + (size_t)c*CLEN)*Dd + d;
  const float fp = (c == 0) ? fprev[b*Dd + d] : 0.0f;
  for (int t = 0; t < CLEN; ++t) {
    const float l = lm[base];
    float bb = bf2f(bgB[base]);
    if (c == 0 && t == 0) bb += l*fp;
    h = l*h + bb;
    const short hr = bf16rne(h);
    fob[base] = hr;
    const float fr = bf2f(hr);
    const float a = bf2f(alB[base]);
    sP *= (1.0f - a);
    sBv = (1.0f - a)*sBv + a*fr;
    base += Dd;
  }
  const size_t ci = ((size_t)b*NCH + c)*Dd + d;
  cPs[ci] = sP; cBs[ci] = sBv;
}

__global__ void s_chunk3(const float* __restrict__ alB_unused_f32, const short* __restrict__ alB,
                         const short* __restrict__ fob, const float* __restrict__ H0s,
                         short* __restrict__ sob)
{
  const int d = blockIdx.x*256 + threadIdx.x;
  const int c = blockIdx.y, b = blockIdx.z;
  float h = H0s[((size_t)b*NCH + c)*Dd + d];
  size_t base = ((size_t)b*Ll + (size_t)c*CLEN)*Dd + d;
  for (int t = 0; t < CLEN; ++t) {
    const float a = bf2f(alB[base]);
    const float f = bf2f(fob[base]);
    h = h + a*(f - h);
    sob[base] = bf16rne(h);
    base += Dd;
  }
}

__global__ void cvt_bf16(const float* __restrict__ src, short* __restrict__ dst, int n4)
{
  int i = blockIdx.x*256 + threadIdx.x;
  const int stride = gridDim.x*256;
  for (; i < n4; i += stride) {
    const f32x4 v = ((const f32x4*)src)[i];
    s16x4 o;
    o[0] = bf16rne(v[0]); o[1] = bf16rne(v[1]);
    o[2] = bf16rne(v[2]); o[3] = bf16rne(v[3]);
    ((s16x4*)dst)[i] = o;
  }
}

extern "C" void kernel_launch(void* const* d_in, const int* in_sizes, int n_in,
                              void* d_out, int out_size, void* d_ws, size_t ws_size,
                              hipStream_t stream)
{
  (void)in_sizes; (void)n_in; (void)out_size; (void)ws_size;
  const float* x   = (const float*)d_in[0];
  const float* fpv = (const float*)d_in[1];
  const float* spv = (const float*)d_in[2];
  const float* wl  = (const float*)d_in[3];
  const float* Pw  = (const float*)d_in[4];
  const float* Wbw = (const float*)d_in[5];
  const float* Waw = (const float*)d_in[6];
  const float* ab  = (const float*)d_in[7];
  const float* Wr  = (const float*)d_in[8];
  const float* rb  = (const float*)d_in[9];
  const float* Wo  = (const float*)d_in[10];
  const float* rs  = (const float*)d_in[11];

  float* out    = (float*)d_out;
  float* f_last = out + (size_t)Mm*Dd;
  float* s_last = f_last + (size_t)Bb*Dd;

  char* w = (char*)d_ws;
  auto alloc = [&](size_t bytes){ char* p = w; w += (bytes + 255) & ~(size_t)255; return p; };
  short* xb   = (short*)alloc((size_t)Mm*Dd*2);
  short* w3   = (short*)alloc((size_t)3*Dd*Dd*2);  // [P_lambda; W_beta; W_alpha], rows=out col
  short* wrb  = (short*)alloc((size_t)Dd*3*Dd*2);
  short* opb  = (short*)alloc((size_t)Dd*Dd*2);
  float* lam  = (float*)alloc((size_t)Mm*Dd*4);
  short* bgB  = (short*)alloc((size_t)Mm*Dd*2);
  short* alB  = (short*)alloc((size_t)Mm*Dd*2);
  short* fb   = (short*)alloc((size_t)Mm*Dd*2);
  short* sb   = (short*)alloc((size_t)Mm*Dd*2);
  float* cP   = (float*)alloc((size_t)Bb*NCH*Dd*4);
  float* cB   = (float*)alloc((size_t)Bb*NCH*Dd*4);
  float* H0   = (float*)alloc((size_t)Bb*NCH*Dd*4);
  short* hm   = (short*)lam;   // alias: lam dead after fs_mid; rho-GEMM output

  auto cvt = [&](const float* s_, short* d_, size_t n){
    int n4 = (int)(n/4);
    int grid = (n4 + 255)/256; if (grid > 2048) grid = 2048;
    cvt_bf16<<<dim3(grid), dim3(256), 0, stream>>>(s_, d_, n4);
  };
  cvt(x,   xb,            (size_t)Mm*Dd);
  cvt(Pw,  w3,            (size_t)Dd*Dd);
  cvt(Wbw, w3 +   Dd*Dd,  (size_t)Dd*Dd);
  cvt(Waw, w3 + 2*Dd*Dd,  (size_t)Dd*Dd);
  cvt(Wr,  wrb,           (size_t)Dd*3*Dd);
  cvt(Wo,  opb,           (size_t)Dd*Dd);

  // fused phase-1: N=3072 (lambda | beta-phi | alpha), 24x64 = 1536 blocks
  gemm_bt<5><<<dim3(3*Dd/128, Mm/128), dim3(256), 0, stream>>>(
      xb, nullptr, nullptr, w3, Dd, wl, ab, nullptr, nullptr, nullptr, nullptr,
      lam, bgB, alB);

  const dim3 gs(Dd/256, NCH, Bb);
  const dim3 gc(Dd/256, Bb);
  f_chunk1<<<gs, dim3(256), 0, stream>>>(lam, bgB, fpv, cP, cB);
  scan_carry<<<gc, dim3(256), 0, stream>>>(cP, cB, (const float*)nullptr, H0, f_last);
  fs_mid<<<gs, dim3(256), 0, stream>>>(lam, bgB, fpv, H0, alB, fb, cP, cB);
  scan_carry<<<gc, dim3(256), 0, stream>>>(cP, cB, spv, H0, s_last);
  s_chunk3<<<gs, dim3(256), 0, stream>>>(nullptr, alB, fb, H0, sb);

  // rho gate GEMM over concat(f,s,x), K=3072; blend epilogue from bf16 f/s
  gemm_bt<3><<<dim3(Dd/128, Mm/128), dim3(256), 0, stream>>>(
      fb, sb, xb, wrb, 3*Dd, rb, nullptr, nullptr, nullptr, fb, sb,
      nullptr, hm, nullptr);

  // out projection + residual
  gemm_bt<4><<<dim3(Dd/128, Mm/128), dim3(256), 0, stream>>>(
      hm, nullptr, nullptr, opb, Dd, nullptr, nullptr, x, rs, nullptr, nullptr,
      out, nullptr, nullptr);
}

// Round 4
// 366.354 us; speedup vs baseline: 1.1278x; 1.0642x over previous
//
#include <hip/hip_runtime.h>

#define Bb 4
#define Ll 2048
#define Dd 1024
#define Mm (Bb*Ll)          // 8192 rows
#define NCH 64              // scan chunks
#define CLEN (Ll/NCH)       // 32 steps per chunk

typedef __attribute__((ext_vector_type(4))) float f32x4;
typedef __attribute__((ext_vector_type(8))) short s16x8;
typedef __attribute__((ext_vector_type(4))) short s16x4;

#define WAITV4 asm volatile("s_waitcnt vmcnt(4)" ::: "memory")
#define WAITV0 asm volatile("s_waitcnt vmcnt(0)" ::: "memory")
#define BARRAW asm volatile("s_barrier" ::: "memory")

__device__ __forceinline__ float sigm(float v){ return 1.0f/(1.0f+__expf(-v)); }

__device__ __forceinline__ short bf16rne(float f){
  unsigned u = __builtin_bit_cast(unsigned, f);
  u += 0x7fffu + ((u>>16)&1u);
  return (short)(u>>16);
}
__device__ __forceinline__ float bf2f(short s){
  unsigned u = ((unsigned)(unsigned short)s) << 16;
  return __builtin_bit_cast(float, u);
}

__device__ __forceinline__ void gl_lds16(const void* g, void* l){
  __builtin_amdgcn_global_load_lds((__attribute__((address_space(1))) void*)g,
                                   (__attribute__((address_space(3))) void*)l, 16, 0, 0);
}

// C[m,n] = sum_k A[m,k] * W[n,k]  (K-contiguous both sides).
// Triple-buffered K-loop, counted vmcnt(4), raw s_barrier (1/step, no vmcnt(0) drain).
// LDS swizzle: logical kseg q of row r stored at slot q ^ ((r>>1)&3)  (16B slots, BK=32).
// EPI: 5=fused phase-1 (lambda-u16|phi|sigmoid by column segment)
//      3=rho-blend->bf16   4=residual out
template<int EPI>
__launch_bounds__(256)
__global__ void gemm_bt(const short* __restrict__ A0, const short* __restrict__ A1,
                        const short* __restrict__ A2, const short* __restrict__ W,
                        int K,
                        const float* __restrict__ b0, const float* __restrict__ b1,
                        const float* __restrict__ xres, const float* __restrict__ rsp,
                        const short* __restrict__ fB, const short* __restrict__ sB,
                        float* __restrict__ oF, unsigned short* __restrict__ oU,
                        short* __restrict__ oB0, short* __restrict__ oB1)
{
  __shared__ short As[3][128*32];
  __shared__ short Bs[3][128*32];
  const int tid  = threadIdx.x;
  const int lane = tid & 63;
  const int wid  = tid >> 6;
  const int wm = wid >> 1, wn = wid & 1;
  const long bn0 = (long)blockIdx.x * 128;
  const long bm0 = (long)blockIdx.y * 128;

  f32x4 acc[4][4] = {};

  const int r0 = tid >> 2;           // staging row, chunk 0 (0..63)
  const int r1 = 64 + r0;            // staging row, chunk 1
  const int j  = tid & 3;            // linear 16B slot within row
  const int sw0 = (j ^ ((r0 >> 1) & 3)) * 8;   // pre-swizzled source kseg (elems)
  const int sw1 = (j ^ ((r1 >> 1) & 3)) * 8;

  auto stage = [&](int buf, int k0){
    const short* Asrc = A0; long acol = k0;
    if (EPI == 3) {
      const int blk = k0 >> 10;
      Asrc = (blk == 0) ? A0 : ((blk == 1) ? A1 : A2);
      acol = k0 & 1023;
    }
    gl_lds16(Asrc + (bm0 + r0)*1024 + acol + sw0, &As[buf][(size_t)tid*8]);
    gl_lds16(Asrc + (bm0 + r1)*1024 + acol + sw1, &As[buf][(size_t)(256+tid)*8]);
    gl_lds16(W + (bn0 + r0)*(long)K + k0 + sw0, &Bs[buf][(size_t)tid*8]);
    gl_lds16(W + (bn0 + r1)*(long)K + k0 + sw1, &Bs[buf][(size_t)(256+tid)*8]);
  };

  auto compute = [&](int buf){
    const int q = lane >> 4;
    s16x8 af[4], bfr[4];
    #pragma unroll
    for (int mi = 0; mi < 4; ++mi) {
      const int row = wm*64 + mi*16 + (lane & 15);
      af[mi] = *(const s16x8*)&As[buf][row*32 + ((q ^ ((row>>1)&3)) << 3)];
    }
    #pragma unroll
    for (int ni = 0; ni < 4; ++ni) {
      const int row = wn*64 + ni*16 + (lane & 15);
      bfr[ni] = *(const s16x8*)&Bs[buf][row*32 + ((q ^ ((row>>1)&3)) << 3)];
    }
    #pragma unroll
    for (int mi = 0; mi < 4; ++mi)
      #pragma unroll
      for (int ni = 0; ni < 4; ++ni)
        asm("v_mfma_f32_16x16x32_bf16 %0, %1, %2, %0"
            : "+v"(acc[mi][ni]) : "v"(af[mi]), "v"(bfr[ni]));
  };

  const int NK = K >> 5;
  // prologue: tiles 0,1 staged; ensure tile 0 complete (4 outstanding = tile 1)
  stage(0, 0);
  stage(1, 32);
  WAITV4;
  BARRAW;
  // invariant at loop top: tile it resident in LDS[it%3]; tile it+1 in flight or resident.
  for (int it = 0; it < NK; ++it) {
    const bool pf = (it + 2) < NK;
    if (pf) stage((it + 2) % 3, (it + 2) << 5);
    compute(it % 3);                 // compiler inserts lgkmcnt before MFMA uses
    if (pf) { WAITV4; } else { WAITV0; }
    BARRAW;                          // all waves: tile it+1 ready; LDS[it%3] reads done
  }

  const float rs = (EPI == 4) ? rsp[0] : 0.0f;
  const int seg = (EPI == 5) ? (int)(bn0 >> 10) : 0;
  const int ecol0 = (int)bn0 + wn*64 + (lane & 15);
  const int erow0 = (int)bm0 + wm*64 + ((lane >> 4) << 2);

  #pragma unroll
  for (int mi = 0; mi < 4; ++mi) {
    #pragma unroll
    for (int ni = 0; ni < 4; ++ni) {
      // MFMA->VALU read hazard fence (inline-asm MFMA: compiler can't insert nops)
      asm volatile("s_nop 7\n\ts_nop 7\n\ts_nop 7" : "+v"(acc[mi][ni]));
      const f32x4 v = acc[mi][ni];
      const int gn = ecol0 + ni*16;
      const int cn = gn & 1023;
      #pragma unroll
      for (int jj = 0; jj < 4; ++jj) {
        const long gm  = erow0 + mi*16 + jj;
        const long idx = gm*1024 + cn;
        const float val = v[jj];
        if (EPI == 5) {
          if (seg == 0) {            // lambda -> u16 fixed point (abs err 7.6e-6)
            float z = val + b0[cn];
            z = fminf(fmaxf(z, -4.0f), 4.0f);
            float l = __expf(-__expf(z));
            l = fminf(fmaxf(l, 0.001f), 0.999f);
            oU[idx] = (unsigned short)__float2uint_rn(l * 65535.0f);
          } else if (seg == 1) {     // B gate: phi = silu + 0.1 sin
            oB0[idx] = bf16rne(val*sigm(val) + 0.1f*__sinf(val));
          } else {                   // alpha
            oB1[idx] = bf16rne(sigm(val + b1[cn]));
          }
        } else if (EPI == 3) {
          const float r = sigm(val + b0[cn]);
          const float f = bf2f(fB[idx]);
          const float s = bf2f(sB[idx]);
          oB0[idx] = bf16rne(r*f + (1.0f - r)*s);
        } else {
          oF[idx] = xres[idx] + rs*val;
        }
      }
    }
  }
}

// ---------- chunked linear-recurrence scans ----------

__global__ void f_chunk1(const unsigned short* __restrict__ lmU, const short* __restrict__ bgB,
                         const float* __restrict__ fprev,
                         float* __restrict__ cP, float* __restrict__ cB)
{
  const int d = blockIdx.x*256 + threadIdx.x;
  const int c = blockIdx.y, b = blockIdx.z;
  float P = 1.0f, Bv = 0.0f;
  size_t base = ((size_t)b*Ll + (size_t)c*CLEN)*Dd + d;
  const float fp = (c == 0) ? fprev[b*Dd + d] : 0.0f;
  for (int t = 0; t < CLEN; ++t) {
    const float l = (float)lmU[base] * (1.0f/65535.0f);
    float bb = bf2f(bgB[base]);
    if (c == 0 && t == 0) bb += l*fp;   // inject f_prev into step 0
    P *= l;
    Bv = l*Bv + bb;
    base += Dd;
  }
  const size_t ci = ((size_t)b*NCH + c)*Dd + d;
  cP[ci] = P; cB[ci] = Bv;
}

__global__ void scan_carry(const float* __restrict__ cP, const float* __restrict__ cB,
                           const float* __restrict__ init,
                           float* __restrict__ H0, float* __restrict__ last_out)
{
  const int d = blockIdx.x*256 + threadIdx.x;
  const int b = blockIdx.y;
  float h = init ? init[b*Dd + d] : 0.0f;
  for (int c = 0; c < NCH; ++c) {
    const size_t ci = ((size_t)b*NCH + c)*Dd + d;
    H0[ci] = h;
    h = cP[ci]*h + cB[ci];
  }
  last_out[b*Dd + d] = h;   // state at t = L-1
}

// f replay (writes bf16 f-states) fused with s-chunk product accumulation.
__global__ void fs_mid(const unsigned short* __restrict__ lmU, const short* __restrict__ bgB,
                       const float* __restrict__ fprev, const float* __restrict__ H0f,
                       const short* __restrict__ alB,
                       short* __restrict__ fob, float* __restrict__ cPs,
                       float* __restrict__ cBs)
{
  const int d = blockIdx.x*256 + threadIdx.x;
  const int c = blockIdx.y, b = blockIdx.z;
  float h = H0f[((size_t)b*NCH + c)*Dd + d];
  float sP = 1.0f, sBv = 0.0f;
  size_t base = ((size_t)b*Ll + (size_t)c*CLEN)*Dd + d;
  const float fp = (c == 0) ? fprev[b*Dd + d] : 0.0f;
  for (int t = 0; t < CLEN; ++t) {
    const float l = (float)lmU[base] * (1.0f/65535.0f);
    float bb = bf2f(bgB[base]);
    if (c == 0 && t == 0) bb += l*fp;
    h = l*h + bb;
    const short hr = bf16rne(h);
    fob[base] = hr;
    const float fr = bf2f(hr);
    const float a = bf2f(alB[base]);
    sP *= (1.0f - a);
    sBv = (1.0f - a)*sBv + a*fr;
    base += Dd;
  }
  const size_t ci = ((size_t)b*NCH + c)*Dd + d;
  cPs[ci] = sP; cBs[ci] = sBv;
}

__global__ void s_chunk3(const short* __restrict__ alB, const short* __restrict__ fob,
                         const float* __restrict__ H0s, short* __restrict__ sob)
{
  const int d = blockIdx.x*256 + threadIdx.x;
  const int c = blockIdx.y, b = blockIdx.z;
  float h = H0s[((size_t)b*NCH + c)*Dd + d];
  size_t base = ((size_t)b*Ll + (size_t)c*CLEN)*Dd + d;
  for (int t = 0; t < CLEN; ++t) {
    const float a = bf2f(alB[base]);
    const float f = bf2f(fob[base]);
    h = h + a*(f - h);
    sob[base] = bf16rne(h);
    base += Dd;
  }
}

// one launch converts all 6 f32 sources into the contiguous bf16 region [xb|w3|wrb|opb]
__global__ void cvt6(const float* __restrict__ a0, const float* __restrict__ a1,
                     const float* __restrict__ a2, const float* __restrict__ a3,
                     const float* __restrict__ a4, const float* __restrict__ a5,
                     short* __restrict__ dst)
{
  const int n0 = (Mm*Dd)/4, n1 = (Dd*Dd)/4, n4 = (3*Dd*Dd)/4;   // vec4 counts
  const int c1 = n0, c2 = c1+n1, c3 = c2+n1, c4 = c3+n1, c5 = c4+n4, total = c5+n1;
  int i = blockIdx.x*256 + threadIdx.x;
  for (; i < total; i += gridDim.x*256) {
    const float* src; int off;
    if      (i < c1) { src = a0; off = i; }
    else if (i < c2) { src = a1; off = i - c1; }
    else if (i < c3) { src = a2; off = i - c2; }
    else if (i < c4) { src = a3; off = i - c3; }
    else if (i < c5) { src = a4; off = i - c4; }
    else             { src = a5; off = i - c5; }
    const f32x4 v = ((const f32x4*)src)[off];
    s16x4 o;
    o[0] = bf16rne(v[0]); o[1] = bf16rne(v[1]);
    o[2] = bf16rne(v[2]); o[3] = bf16rne(v[3]);
    ((s16x4*)dst)[i] = o;
  }
}

extern "C" void kernel_launch(void* const* d_in, const int* in_sizes, int n_in,
                              void* d_out, int out_size, void* d_ws, size_t ws_size,
                              hipStream_t stream)
{
  (void)in_sizes; (void)n_in; (void)out_size; (void)ws_size;
  const float* x   = (const float*)d_in[0];
  const float* fpv = (const float*)d_in[1];
  const float* spv = (const float*)d_in[2];
  const float* wl  = (const float*)d_in[3];
  const float* Pw  = (const float*)d_in[4];
  const float* Wbw = (const float*)d_in[5];
  const float* Waw = (const float*)d_in[6];
  const float* ab  = (const float*)d_in[7];
  const float* Wr  = (const float*)d_in[8];
  const float* rb  = (const float*)d_in[9];
  const float* Wo  = (const float*)d_in[10];
  const float* rs  = (const float*)d_in[11];

  float* out    = (float*)d_out;
  float* f_last = out + (size_t)Mm*Dd;
  float* s_last = f_last + (size_t)Bb*Dd;

  char* w = (char*)d_ws;
  auto alloc = [&](size_t bytes){ char* p = w; w += (bytes + 255) & ~(size_t)255; return p; };
  short* xb   = (short*)alloc((size_t)Mm*Dd*2);     // contiguous bf16 region start
  short* w3   = (short*)alloc((size_t)3*Dd*Dd*2);   // [P_lambda; W_beta; W_alpha]
  short* wrb  = (short*)alloc((size_t)Dd*3*Dd*2);
  short* opb  = (short*)alloc((size_t)Dd*Dd*2);
  unsigned short* lamU = (unsigned short*)alloc((size_t)Mm*Dd*2);
  short* bgB  = (short*)alloc((size_t)Mm*Dd*2);
  short* alB  = (short*)alloc((size_t)Mm*Dd*2);
  short* fb   = (short*)alloc((size_t)Mm*Dd*2);
  short* sb   = (short*)alloc((size_t)Mm*Dd*2);
  float* cP   = (float*)alloc((size_t)Bb*NCH*Dd*4);
  float* cB   = (float*)alloc((size_t)Bb*NCH*Dd*4);
  float* H0   = (float*)alloc((size_t)Bb*NCH*Dd*4);
  short* hm   = (short*)lamU;   // alias: lamU dead after fs_mid; rho-GEMM output

  cvt6<<<dim3(2048), dim3(256), 0, stream>>>(x, Pw, Wbw, Waw, Wr, Wo, xb);

  // fused phase-1: N=3072 (lambda | beta-phi | alpha), 24x64 = 1536 blocks
  gemm_bt<5><<<dim3(3*Dd/128, Mm/128), dim3(256), 0, stream>>>(
      xb, nullptr, nullptr, w3, Dd, wl, ab, nullptr, nullptr, nullptr, nullptr,
      nullptr, lamU, bgB, alB);

  const dim3 gs(Dd/256, NCH, Bb);
  const dim3 gc(Dd/256, Bb);
  f_chunk1<<<gs, dim3(256), 0, stream>>>(lamU, bgB, fpv, cP, cB);
  scan_carry<<<gc, dim3(256), 0, stream>>>(cP, cB, (const float*)nullptr, H0, f_last);
  fs_mid<<<gs, dim3(256), 0, stream>>>(lamU, bgB, fpv, H0, alB, fb, cP, cB);
  scan_carry<<<gc, dim3(256), 0, stream>>>(cP, cB, spv, H0, s_last);
  s_chunk3<<<gs, dim3(256), 0, stream>>>(alB, fb, H0, sb);

  // rho gate GEMM over concat(f,s,x), K=3072; blend epilogue from bf16 f/s
  gemm_bt<3><<<dim3(Dd/128, Mm/128), dim3(256), 0, stream>>>(
      fb, sb, xb, wrb, 3*Dd, rb, nullptr, nullptr, nullptr, fb, sb,
      nullptr, nullptr, hm, nullptr);

  // out projection + residual
  gemm_bt<4><<<dim3(Dd/128, Mm/128), dim3(256), 0, stream>>>(
      hm, nullptr, nullptr, opb, Dd, nullptr, nullptr, x, rs, nullptr, nullptr,
      out, nullptr, nullptr, nullptr);
}